// Round 9
// baseline (6033.067 us; speedup 1.0000x reference)
//
#include <hip/hip_runtime.h>

typedef short short8 __attribute__((ext_vector_type(8)));
typedef float f32x4 __attribute__((ext_vector_type(4)));
typedef unsigned int u32x4 __attribute__((ext_vector_type(4)));
typedef unsigned int u32x2 __attribute__((ext_vector_type(2)));

#define T_STEPS 512
#define BATCH   128
#define EMBD    512
#define HID     1024
#define NWG     256
#define NTHR    1024
#define NGROUP  8
#define WPG     32

// ---- workspace layout (bytes) ----
// ctrl: u32[64..575]: flags, 8 groups * 64 u32 (256 B per group, 256B-aligned)
#define CTRL_BYTES 4096
#define H_OFF     CTRL_BYTES
#define H_BYTES   (NGROUP * 2 * 32768)            // 524288
#define WH_OFF    (H_OFF + H_BYTES)
#define WH_BYTES  (32u*32u*8u*64u*8u*2u)          // 8388608
#define WI_OFF    (WH_OFF + WH_BYTES)
#define WI_BYTES  (32u*16u*8u*64u*8u*2u)          // 4194304
#define BS_OFF    (WI_OFF + WI_BYTES)
#define BS_BYTES  (4096 * 4)
#define PT_OFF    (BS_OFF + BS_BYTES)
#define PT_BYTES  (BATCH * 32 * 2 * 4)
#define EMB_OFF   (PT_OFF + PT_BYTES)
#define EMB_BYTES ((size_t)T_STEPS*16*8*64*8*2)   // 67108864
#define WS_NEEDED (EMB_OFF + EMB_BYTES)

#define POLL_CAP  (1u << 17)   // bounded spin: worst case ~tens of ms, never a timeout

__device__ __forceinline__ unsigned short f2b(float f) {
    unsigned u = __builtin_bit_cast(unsigned, f);
    u += 0x7FFFu + ((u >> 16) & 1u);
    return (unsigned short)(u >> 16);
}

__device__ __forceinline__ uint4 pack8(float4 a, float4 b) {
    uint4 r;
    r.x = (unsigned)f2b(a.x) | ((unsigned)f2b(a.y) << 16);
    r.y = (unsigned)f2b(a.z) | ((unsigned)f2b(a.w) << 16);
    r.z = (unsigned)f2b(b.x) | ((unsigned)f2b(b.y) << 16);
    r.w = (unsigned)f2b(b.z) | ((unsigned)f2b(b.w) << 16);
    return r;
}

__device__ __forceinline__ float fsig(float x) {
    float e = __expf(-fabsf(x));
    float r = 1.f / (1.f + e);
    return x >= 0.f ? r : 1.f - r;
}
__device__ __forceinline__ float ftanh_(float x) {
    float e = __expf(-2.f * fabsf(x));
    float r = (1.f - e) / (1.f + e);
    return x >= 0.f ? r : -r;
}

// LLC-coherent ops (sc0 sc1) — the R5-proven protocol; no XCD-locality assumptions
__device__ __forceinline__ void llc_load16(const void* p, u32x4& v) {
    asm volatile("global_load_dwordx4 %0, %1, off sc0 sc1" : "=v"(v) : "v"(p));
}
__device__ __forceinline__ unsigned llc_load4(const void* p) {
    unsigned v;
    asm volatile("global_load_dword %0, %1, off sc0 sc1\n\ts_waitcnt vmcnt(0)"
                 : "=v"(v) : "v"(p) : "memory");
    return v;
}
__device__ __forceinline__ void llc_store8(void* p, u32x2 v) {
    asm volatile("global_store_dwordx2 %0, %1, off sc0 sc1" :: "v"(p), "v"(v) : "memory");
}
__device__ __forceinline__ void llc_store4(void* p, unsigned v) {
    asm volatile("global_store_dword %0, %1, off sc0 sc1" :: "v"(p), "v"(v) : "memory");
}
__device__ __forceinline__ void waitvm0() {
    asm volatile("s_waitcnt vmcnt(0)" ::: "memory");
}

// W_hh [4096,1024] -> wh_arr[w][ks(32)][nq(8)][lane][8]
__global__ void prep_wh(const float* __restrict__ w_hh, unsigned short* __restrict__ wh_arr) {
    int gid = blockIdx.x * blockDim.x + threadIdx.x;   // < 524288
    int l  = gid & 63;
    int nq = (gid >> 6) & 7;
    int ks = (gid >> 9) & 31;
    int w  = gid >> 14;
    int lr = nq * 16 + (l & 15);                       // 0..127
    int grow = (lr >> 5) * HID + w * 32 + (lr & 31);   // gate*1024 + col
    int k = ks * 32 + (l >> 4) * 8;
    const float4* src = reinterpret_cast<const float4*>(w_hh + (size_t)grow * HID + k);
    *reinterpret_cast<uint4*>(wh_arr + (size_t)gid * 8) = pack8(src[0], src[1]);
}

// W_ih [4096,512] -> wi_arr[w][eks(16)][nq(8)][lane][8]
__global__ void prep_wi(const float* __restrict__ w_ih, unsigned short* __restrict__ wi_arr) {
    int gid = blockIdx.x * blockDim.x + threadIdx.x;   // < 262144
    int l  = gid & 63;
    int nq = (gid >> 6) & 7;
    int eks = (gid >> 9) & 15;
    int w  = gid >> 13;
    int lr = nq * 16 + (l & 15);
    int grow = (lr >> 5) * HID + w * 32 + (lr & 31);
    int k = eks * 32 + (l >> 4) * 8;
    const float4* src = reinterpret_cast<const float4*>(w_ih + (size_t)grow * EMBD + k);
    *reinterpret_cast<uint4*>(wi_arr + (size_t)gid * 8) = pack8(src[0], src[1]);
}

__global__ void prep_bsum(const float* __restrict__ b_ih, const float* __restrict__ b_hh,
                          float* __restrict__ bs) {
    int gid = blockIdx.x * blockDim.x + threadIdx.x;   // < 4096
    int w = gid >> 7, lr = gid & 127;
    int grow = (lr >> 5) * HID + w * 32 + (lr & 31);
    bs[gid] = b_ih[grow] + b_hh[grow];
}

// embedded bf16 fragment chunks: emb_arr[t][eks(16)][mt(8)][lane][8]  (mt == group)
__global__ void prep_emb(const int* __restrict__ x, const float* __restrict__ emb,
                         unsigned short* __restrict__ emb_arr) {
    int gid = blockIdx.x * blockDim.x + threadIdx.x;   // < 512*16*8*64
    int l  = gid & 63;
    int mt = (gid >> 6) & 7;
    int ks = (gid >> 9) & 15;
    int t  = gid >> 13;
    int b  = mt * 16 + (l & 15);
    int k  = ks * 32 + (l >> 4) * 8;
    int tok = x[t * BATCH + b];
    const float4* src = reinterpret_cast<const float4*>(emb + (size_t)tok * EMBD + k);
    *reinterpret_cast<uint4*>(emb_arr + (size_t)gid * 8) = pack8(src[0], src[1]);
}

__global__ __launch_bounds__(NTHR) void lstm_main(
    const unsigned short* __restrict__ wh_arr,
    const unsigned short* __restrict__ wi_arr,
    const float* __restrict__ bs_arr,
    const unsigned short* __restrict__ emb_arr,
    unsigned short* __restrict__ h_arr,
    const float* __restrict__ fc_w,
    float* __restrict__ partials,
    unsigned* __restrict__ ctrl)
{
    __shared__ __align__(16) unsigned short wis[16 * 8 * 64 * 8];  // 131072 B
    __shared__ __align__(16) char ovl[32768];                      // stage / gbuf / fc overlay
    float* gbf    = reinterpret_cast<float*>(ovl);                 // [2][16][132]
    u32x4* stage4 = reinterpret_cast<u32x4*>(ovl);
    unsigned short* stage = reinterpret_cast<unsigned short*>(ovl);

    unsigned* flags = ctrl + 64;   // 8 groups * 64 u32, packed 256 B per group

    const int tid = threadIdx.x;
    const int g = (int)(blockIdx.x >> 5);   // group 0..7 (batch rows 16g..16g+15)
    const int w = (int)(blockIdx.x & 31);   // gate-slice 0..31

    {   // one-time LDS fill of W_ih slice
        const uint4* s2 = reinterpret_cast<const uint4*>(wi_arr + (size_t)w * 65536);
        uint4* d2 = reinterpret_cast<uint4*>(wis);
        for (int i = tid; i < 8192; i += NTHR) d2[i] = s2[i];
    }

    const int lane = tid & 63;
    const int wave = tid >> 6;    // 0..15
    const int nq   = wave >> 1;   // n-tile 0..7 (16 gate rows each)
    const int kq   = wave & 1;    // k-half

    // W_hh B-fragments: persistent registers
    short8 bh[16];
    #pragma unroll
    for (int s = 0; s < 16; ++s) {
        int ks = kq * 16 + s;
        bh[s] = *reinterpret_cast<const short8*>(wh_arr + (size_t)(((w * 32 + ks) * 8 + nq) * 64 + lane) * 8);
    }

    // bias folded into acc-init (kq==0 only); D col n = lrD
    const int lrD   = nq * 16 + (lane & 15);
    const int rbase = (lane >> 4) * 4;
    const float bini = (kq == 0) ? bs_arr[w * 128 + lrD] : 0.f;

    // pointwise ownership (tid<128): batch row pb, col quad qd
    const int pb = tid & 15;
    const int qd = tid >> 4;       // 0..7 when tid<128
    float cs[4] = {0.f, 0.f, 0.f, 0.f};
    float hr[4] = {0.f, 0.f, 0.f, 0.f};

    __syncthreads();   // wis ready

    for (int t = 0; t < T_STEPS; ++t) {
        const unsigned tu = (unsigned)t;
        f32x4 acc = {bini, bini, bini, bini};
        u32x4 v0, v1;

        if (t > 0) {
            // ---- poll: wave 15, one coalesced 256B flag read per iteration ----
            if (wave == 15) {
                const unsigned* fl = flags + g * 64 + lane;
                unsigned spins = 0;
                for (;;) {
                    unsigned v = llc_load4(fl);
                    if (__all((int)(v >= tu))) break;
                    if (++spins > POLL_CAP) break;
                    asm volatile("s_sleep 1");
                }
            }
            __syncthreads();                       // S1: h_t published; prior gbf reads done

            // ---- issue stage loads; emb MFMA runs underneath ----
            const char* hb = reinterpret_cast<const char*>(h_arr) + (size_t)(g * 2 + (t & 1)) * 32768;
            llc_load16(hb + tid * 16, v0);
            llc_load16(hb + (tid + 1024) * 16, v1);
        }

        // ---- emb part (independent of h) ----
        const unsigned short* ebuf = emb_arr + (size_t)t * 65536;
        #pragma unroll
        for (int s = 0; s < 8; ++s) {
            int eks = kq * 8 + s;
            short8 a  = *reinterpret_cast<const short8*>(ebuf + ((eks * 8 + g) * 64 + lane) * 8);
            short8 bw = *reinterpret_cast<const short8*>(wis + ((eks * 8 + nq) * 64 + lane) * 8);
            acc = __builtin_amdgcn_mfma_f32_16x16x32_bf16(a, bw, acc, 0, 0, 0);
        }

        if (t > 0) {
            waitvm0();
            __builtin_amdgcn_sched_barrier(0);
            stage4[tid] = v0;
            stage4[tid + 1024] = v1;
            __syncthreads();                       // S2: stage ready

            #pragma unroll
            for (int s = 0; s < 16; ++s) {
                int ks = kq * 16 + s;
                short8 a = *reinterpret_cast<const short8*>(stage + (ks * 64 + lane) * 8);
                acc = __builtin_amdgcn_mfma_f32_16x16x32_bf16(a, bh[s], acc, 0, 0, 0);
            }
        }
        __syncthreads();                           // S3: stage reads done before gbf overwrite

        #pragma unroll
        for (int jj = 0; jj < 4; ++jj)
            gbf[kq * 2112 + (rbase + jj) * 132 + lrD] = acc[jj];
        __syncthreads();                           // S4: gates ready

        if (tid < 128) {   // pointwise: 4 cols (qd*4..+4) of batch row pb
            const float* g0 = gbf + pb * 132;
            const float* g1 = gbf + 2112 + pb * 132;
            const int cb = qd * 4;
            float4 xi = *reinterpret_cast<const float4*>(g0 + cb);
            float4 xf = *reinterpret_cast<const float4*>(g0 + 32 + cb);
            float4 xg = *reinterpret_cast<const float4*>(g0 + 64 + cb);
            float4 xo = *reinterpret_cast<const float4*>(g0 + 96 + cb);
            float4 yi = *reinterpret_cast<const float4*>(g1 + cb);
            float4 yf = *reinterpret_cast<const float4*>(g1 + 32 + cb);
            float4 yg = *reinterpret_cast<const float4*>(g1 + 64 + cb);
            float4 yo = *reinterpret_cast<const float4*>(g1 + 96 + cb);
            float ti[4] = {xi.x + yi.x, xi.y + yi.y, xi.z + yi.z, xi.w + yi.w};
            float tf[4] = {xf.x + yf.x, xf.y + yf.y, xf.z + yf.z, xf.w + yf.w};
            float tg[4] = {xg.x + yg.x, xg.y + yg.y, xg.z + yg.z, xg.w + yg.w};
            float to[4] = {xo.x + yo.x, xo.y + yo.y, xo.z + yo.z, xo.w + yo.w};
            #pragma unroll
            for (int e = 0; e < 4; ++e) {
                float ig = fsig(ti[e]), fg = fsig(tf[e]), gg = ftanh_(tg[e]), og = fsig(to[e]);
                cs[e] = fg * cs[e] + ig * gg;
                hr[e] = og * ftanh_(cs[e]);
            }
            u32x2 pk;
            pk.x = (unsigned)f2b(hr[0]) | ((unsigned)f2b(hr[1]) << 16);
            pk.y = (unsigned)f2b(hr[2]) | ((unsigned)f2b(hr[3]) << 16);
            char* hd = reinterpret_cast<char*>(h_arr) + (size_t)(g * 2 + ((t + 1) & 1)) * 32768;
            llc_store8(hd + (w * 64 + (qd >> 1) * 16 + pb) * 16 + (qd & 1) * 8, pk);
            waitvm0();   // this wave's h slice acked at LLC
            if ((tid & 63) == 0) {
                // per-pointwise-wave flag: h visible before flag (program order after vmcnt(0))
                llc_store4(flags + g * 64 + w * 2 + (tid >> 6), tu + 1u);
            }
        }
        // no trailing barrier: consumers gate on flags; S1 orders LDS reuse
    }

    // ---- FC head: deterministic two-stage reduce via LDS ----
    __syncthreads();
    float* red = reinterpret_cast<float*>(ovl);
    if (tid < 128) {
        float v0f = 0.f, v1f = 0.f;
        #pragma unroll
        for (int e = 0; e < 4; ++e) {
            int col = w * 32 + qd * 4 + e;
            v0f += hr[e] * fc_w[col];
            v1f += hr[e] * fc_w[HID + col];
        }
        red[tid * 2]     = v0f;
        red[tid * 2 + 1] = v1f;
    }
    __syncthreads();
    if (tid < 32) {
        int b = tid >> 1, o = tid & 1;
        float s = 0.f;
        for (int q = 0; q < 8; ++q) s += red[((q << 4) | b) * 2 + o];
        partials[((g * 16 + b) * 32 + w) * 2 + o] = s;
    }
}

__global__ void finalize(const float* __restrict__ partials, const float* __restrict__ fc_b,
                         float* __restrict__ out) {
    int tid = threadIdx.x;             // 256
    int b = tid >> 1, o = tid & 1;
    float s = fc_b[o];
    for (int w = 0; w < 32; ++w) s += partials[(b * 32 + w) * 2 + o];
    out[b * 2 + o] = s;
}

extern "C" void kernel_launch(void* const* d_in, const int* in_sizes, int n_in,
                              void* d_out, int out_size, void* d_ws, size_t ws_size,
                              hipStream_t stream) {
    const int*   x    = (const int*)d_in[0];
    const float* emb  = (const float*)d_in[1];
    const float* w_ih = (const float*)d_in[2];
    const float* w_hh = (const float*)d_in[3];
    const float* b_ih = (const float*)d_in[4];
    const float* b_hh = (const float*)d_in[5];
    const float* fc_w = (const float*)d_in[6];
    const float* fc_b = (const float*)d_in[7];
    float* out = (float*)d_out;
    char* ws = (char*)d_ws;

    if (ws_size < WS_NEEDED) {
        (void)hipMemsetAsync(d_out, 0xFF, (size_t)out_size * sizeof(float), stream);
        return;
    }

    unsigned*       ctrl    = (unsigned*)(ws);
    unsigned short* h_arr   = (unsigned short*)(ws + H_OFF);
    unsigned short* wh_arr  = (unsigned short*)(ws + WH_OFF);
    unsigned short* wi_arr  = (unsigned short*)(ws + WI_OFF);
    float*          bs_arr  = (float*)(ws + BS_OFF);
    float*          pt_arr  = (float*)(ws + PT_OFF);
    unsigned short* emb_arr = (unsigned short*)(ws + EMB_OFF);

    // zero flags (in-stream: re-zeroed every replay)
    (void)hipMemsetAsync(ws, 0, CTRL_BYTES, stream);

    prep_wh  <<<2048, 256, 0, stream>>>(w_hh, wh_arr);
    prep_wi  <<<1024, 256, 0, stream>>>(w_ih, wi_arr);
    prep_bsum<<<16,   256, 0, stream>>>(b_ih, b_hh, bs_arr);
    prep_emb <<<16384,256, 0, stream>>>(x, emb, emb_arr);
    lstm_main<<<NWG, NTHR, 0, stream>>>(wh_arr, wi_arr, bs_arr, emb_arr, h_arr,
                                        fc_w, pt_arr, ctrl);
    finalize <<<1, 256, 0, stream>>>(pt_arr, fc_b, out);
}

// Round 12
// 5101.251 us; speedup vs baseline: 1.1827x; 1.1827x over previous
//
#include <hip/hip_runtime.h>

typedef short short8 __attribute__((ext_vector_type(8)));
typedef float f32x4 __attribute__((ext_vector_type(4)));
typedef unsigned int u32x2 __attribute__((ext_vector_type(2)));
typedef unsigned long long u64;
typedef unsigned long long u64x2 __attribute__((ext_vector_type(2)));

#define T_STEPS 512
#define BATCH   128
#define EMBD    512
#define HID     1024
#define NWG     256
#define NTHR    1024
#define NGROUP  8
#define WPG     32

// ---- workspace layout (bytes) ----
// ctrl: flags, 8 groups * 1024 u32 (4 KB per group; slot = (w*2+pw)*16 u32, 64B-strided)
#define CTRL_BYTES 65536
#define H_OFF     CTRL_BYTES
#define H_BYTES   (NGROUP * 2 * 32768)            // 524288
#define WH_OFF    (H_OFF + H_BYTES)
#define WH_BYTES  (32u*32u*8u*64u*8u*2u)          // 8388608
#define WI_OFF    (WH_OFF + WH_BYTES)
#define WI_BYTES  (32u*16u*8u*64u*8u*2u)          // 4194304
#define BS_OFF    (WI_OFF + WI_BYTES)
#define BS_BYTES  (4096 * 4)
#define PT_OFF    (BS_OFF + BS_BYTES)
#define PT_BYTES  (BATCH * 32 * 2 * 4)
#define EMB_OFF   (PT_OFF + PT_BYTES)
#define EMB_BYTES ((size_t)T_STEPS*16*8*64*8*2)   // 67108864
#define WS_NEEDED (EMB_OFF + EMB_BYTES)

#define POLL_CAP  (1u << 17)   // bounded global spin; never a harness timeout
#define LDS_CAP   (1u << 21)   // bounded LDS spin
#define GO_OFF    20480        // byte offset of 'go' word inside ovl (gbf uses < 16896)

__device__ __forceinline__ unsigned short f2b(float f) {
    unsigned u = __builtin_bit_cast(unsigned, f);
    u += 0x7FFFu + ((u >> 16) & 1u);
    return (unsigned short)(u >> 16);
}

__device__ __forceinline__ uint4 pack8(float4 a, float4 b) {
    uint4 r;
    r.x = (unsigned)f2b(a.x) | ((unsigned)f2b(a.y) << 16);
    r.y = (unsigned)f2b(a.z) | ((unsigned)f2b(a.w) << 16);
    r.z = (unsigned)f2b(b.x) | ((unsigned)f2b(b.y) << 16);
    r.w = (unsigned)f2b(b.z) | ((unsigned)f2b(b.w) << 16);
    return r;
}

__device__ __forceinline__ float fsig(float x) {
    float e = __expf(-fabsf(x));
    float r = 1.f / (1.f + e);
    return x >= 0.f ? r : 1.f - r;
}
__device__ __forceinline__ float ftanh_(float x) {
    float e = __expf(-2.f * fabsf(x));
    float r = (1.f - e) / (1.f + e);
    return x >= 0.f ? r : -r;
}

// LLC-coherent primitive ops (sc0 sc1) — R5-proven protocol pieces
__device__ __forceinline__ unsigned llc_load4(const void* p) {
    unsigned v;
    asm volatile("global_load_dword %0, %1, off sc0 sc1\n\ts_waitcnt vmcnt(0)"
                 : "=v"(v) : "v"(p) : "memory");
    return v;
}
__device__ __forceinline__ void llc_store8(void* p, u32x2 v) {
    asm volatile("global_store_dwordx2 %0, %1, off sc0 sc1" :: "v"(p), "v"(v) : "memory");
}
__device__ __forceinline__ void llc_store4(void* p, unsigned v) {
    asm volatile("global_store_dword %0, %1, off sc0 sc1" :: "v"(p), "v"(v) : "memory");
}
__device__ __forceinline__ void waitvm0() {
    asm volatile("s_waitcnt vmcnt(0)" ::: "memory");
}
// coherent 8B load, compiler-scheduled (no manual vmcnt) — mechanism proven in R5
__device__ __forceinline__ u64 coh_load8(const void* p) {
    return __hip_atomic_load((const u64*)p, __ATOMIC_RELAXED, __HIP_MEMORY_SCOPE_AGENT);
}

// W_hh [4096,1024] -> wh_arr[w][ks(32)][nq(8)][lane][8]
__global__ void prep_wh(const float* __restrict__ w_hh, unsigned short* __restrict__ wh_arr) {
    int gid = blockIdx.x * blockDim.x + threadIdx.x;   // < 524288
    int l  = gid & 63;
    int nq = (gid >> 6) & 7;
    int ks = (gid >> 9) & 31;
    int w  = gid >> 14;
    int lr = nq * 16 + (l & 15);                       // 0..127
    int grow = (lr >> 5) * HID + w * 32 + (lr & 31);   // gate*1024 + col
    int k = ks * 32 + (l >> 4) * 8;
    const float4* src = reinterpret_cast<const float4*>(w_hh + (size_t)grow * HID + k);
    *reinterpret_cast<uint4*>(wh_arr + (size_t)gid * 8) = pack8(src[0], src[1]);
}

// W_ih [4096,512] -> wi_arr[w][eks(16)][nq(8)][lane][8]
__global__ void prep_wi(const float* __restrict__ w_ih, unsigned short* __restrict__ wi_arr) {
    int gid = blockIdx.x * blockDim.x + threadIdx.x;   // < 262144
    int l  = gid & 63;
    int nq = (gid >> 6) & 7;
    int eks = (gid >> 9) & 15;
    int w  = gid >> 13;
    int lr = nq * 16 + (l & 15);
    int grow = (lr >> 5) * HID + w * 32 + (lr & 31);
    int k = eks * 32 + (l >> 4) * 8;
    const float4* src = reinterpret_cast<const float4*>(w_ih + (size_t)grow * EMBD + k);
    *reinterpret_cast<uint4*>(wi_arr + (size_t)gid * 8) = pack8(src[0], src[1]);
}

__global__ void prep_bsum(const float* __restrict__ b_ih, const float* __restrict__ b_hh,
                          float* __restrict__ bs) {
    int gid = blockIdx.x * blockDim.x + threadIdx.x;   // < 4096
    int w = gid >> 7, lr = gid & 127;
    int grow = (lr >> 5) * HID + w * 32 + (lr & 31);
    bs[gid] = b_ih[grow] + b_hh[grow];
}

// embedded bf16 fragment chunks: emb_arr[t][eks(16)][mt(8)][lane][8]  (mt == group)
__global__ void prep_emb(const int* __restrict__ x, const float* __restrict__ emb,
                         unsigned short* __restrict__ emb_arr) {
    int gid = blockIdx.x * blockDim.x + threadIdx.x;   // < 512*16*8*64
    int l  = gid & 63;
    int mt = (gid >> 6) & 7;
    int ks = (gid >> 9) & 15;
    int t  = gid >> 13;
    int b  = mt * 16 + (l & 15);
    int k  = ks * 32 + (l >> 4) * 8;
    int tok = x[t * BATCH + b];
    const float4* src = reinterpret_cast<const float4*>(emb + (size_t)tok * EMBD + k);
    *reinterpret_cast<uint4*>(emb_arr + (size_t)gid * 8) = pack8(src[0], src[1]);
}

__global__ __launch_bounds__(NTHR) void lstm_main(
    const unsigned short* __restrict__ wh_arr,
    const unsigned short* __restrict__ wi_arr,
    const float* __restrict__ bs_arr,
    const unsigned short* __restrict__ emb_arr,
    unsigned short* __restrict__ h_arr,
    const float* __restrict__ fc_w,
    float* __restrict__ partials,
    unsigned* __restrict__ ctrl)
{
    __shared__ __align__(16) unsigned short wis[16 * 8 * 64 * 8];  // 131072 B
    __shared__ __align__(16) char ovl[32768];                      // gbf / fc / go overlay
    float* gbf = reinterpret_cast<float*>(ovl);                    // [2][16][132] = 16896 B
    unsigned* go_p = reinterpret_cast<unsigned*>(ovl + GO_OFF);    // disjoint from gbf/red

    const int tid = threadIdx.x;
    const int g = (int)(blockIdx.x >> 5);   // group 0..7 (batch rows 16g..16g+15)
    const int w = (int)(blockIdx.x & 31);   // gate-slice 0..31

    {   // one-time LDS fill of W_ih slice
        const uint4* s2 = reinterpret_cast<const uint4*>(wi_arr + (size_t)w * 65536);
        uint4* d2 = reinterpret_cast<uint4*>(wis);
        for (int i = tid; i < 8192; i += NTHR) d2[i] = s2[i];
    }
    if (tid == 0) *go_p = 0;

    const int lane = tid & 63;
    const int wave = tid >> 6;    // 0..15
    const int nq   = wave >> 1;   // n-tile 0..7 (16 gate rows each)
    const int kq   = wave & 1;    // k-half

    // W_hh B-fragments: persistent registers
    short8 bh[16];
    #pragma unroll
    for (int s = 0; s < 16; ++s) {
        int ks = kq * 16 + s;
        bh[s] = *reinterpret_cast<const short8*>(wh_arr + (size_t)(((w * 32 + ks) * 8 + nq) * 64 + lane) * 8);
    }

    // bias folded into acc-init (kq==0 only); D col n = lrD
    const int lrD   = nq * 16 + (lane & 15);
    const int rbase = (lane >> 4) * 4;
    const float bini = (kq == 0) ? bs_arr[w * 128 + lrD] : 0.f;

    // pointwise ownership (tid<128): batch row pb, col quad qd
    const int pb = tid & 15;
    const int qd = tid >> 4;       // 0..7 when tid<128
    float cs[4] = {0.f, 0.f, 0.f, 0.f};
    float hr[4] = {0.f, 0.f, 0.f, 0.f};

    unsigned* flags = ctrl + g * 1024;   // 64 slots * 16 u32 (64B-strided)

    __syncthreads();   // wis + go ready

    for (int t = 0; t < T_STEPS; ++t) {
        const unsigned tu = (unsigned)t;
        f32x4 acc = {bini, bini, bini, bini};

        // ---- wave 15 polls while waves 0..14 run emb MFMA ----
        if (t > 0 && wave == 15) {
            const unsigned* fl = flags + lane * 16;
            unsigned spins = 0;
            for (;;) {
                unsigned v = llc_load4(fl);
                if (__all((int)(v >= tu))) break;
                if (++spins > POLL_CAP) break;
            }
            if (lane == 0)
                __hip_atomic_store(go_p, tu, __ATOMIC_RELEASE, __HIP_MEMORY_SCOPE_WORKGROUP);
        }

        // ---- emb part (independent of h) ----
        const unsigned short* ebuf = emb_arr + (size_t)t * 65536;
        #pragma unroll
        for (int s = 0; s < 8; ++s) {
            int eks = kq * 8 + s;
            short8 a  = *reinterpret_cast<const short8*>(ebuf + ((eks * 8 + g) * 64 + lane) * 8);
            short8 bw = *reinterpret_cast<const short8*>(wis + ((eks * 8 + nq) * 64 + lane) * 8);
            acc = __builtin_amdgcn_mfma_f32_16x16x32_bf16(a, bw, acc, 0, 0, 0);
        }

        if (t > 0) {
            if (wave != 15) {
                unsigned spins = 0;
                while (__hip_atomic_load(go_p, __ATOMIC_ACQUIRE, __HIP_MEMORY_SCOPE_WORKGROUP) < tu
                       && ++spins < LDS_CAP) {}
            }

            // ---- h A-fragments direct to registers: 4 chunks of 4 frags (coherent 8B loads,
            //      compiler-managed waits — no manual vmcnt, no inline-asm loads) ----
            const char* hbase = reinterpret_cast<const char*>(h_arr)
                              + (size_t)(g * 2 + (t & 1)) * 32768 + (size_t)kq * 16384 + (size_t)lane * 16;
            #pragma unroll
            for (int c = 0; c < 4; ++c) {
                const char* p0 = hbase + (c * 4 + 0) * 1024;
                const char* p1 = hbase + (c * 4 + 1) * 1024;
                const char* p2 = hbase + (c * 4 + 2) * 1024;
                const char* p3 = hbase + (c * 4 + 3) * 1024;
                u64x2 q0, q1, q2, q3;
                q0.x = coh_load8(p0); q0.y = coh_load8(p0 + 8);
                q1.x = coh_load8(p1); q1.y = coh_load8(p1 + 8);
                q2.x = coh_load8(p2); q2.y = coh_load8(p2 + 8);
                q3.x = coh_load8(p3); q3.y = coh_load8(p3 + 8);
                acc = __builtin_amdgcn_mfma_f32_16x16x32_bf16(__builtin_bit_cast(short8, q0), bh[c * 4 + 0], acc, 0, 0, 0);
                acc = __builtin_amdgcn_mfma_f32_16x16x32_bf16(__builtin_bit_cast(short8, q1), bh[c * 4 + 1], acc, 0, 0, 0);
                acc = __builtin_amdgcn_mfma_f32_16x16x32_bf16(__builtin_bit_cast(short8, q2), bh[c * 4 + 2], acc, 0, 0, 0);
                acc = __builtin_amdgcn_mfma_f32_16x16x32_bf16(__builtin_bit_cast(short8, q3), bh[c * 4 + 3], acc, 0, 0, 0);
            }
        }

        __syncthreads();                             // SYNC_A: prev pointwise gbf reads done

        #pragma unroll
        for (int jj = 0; jj < 4; ++jj)
            gbf[kq * 2112 + (rbase + jj) * 132 + lrD] = acc[jj];
        __syncthreads();                             // S4: gates ready

        if (tid < 128) {   // pointwise: 4 cols (qd*4..+4) of batch row pb
            const float* g0 = gbf + pb * 132;
            const float* g1 = gbf + 2112 + pb * 132;
            const int cb = qd * 4;
            float4 xi = *reinterpret_cast<const float4*>(g0 + cb);
            float4 xf = *reinterpret_cast<const float4*>(g0 + 32 + cb);
            float4 xg = *reinterpret_cast<const float4*>(g0 + 64 + cb);
            float4 xo = *reinterpret_cast<const float4*>(g0 + 96 + cb);
            float4 yi = *reinterpret_cast<const float4*>(g1 + cb);
            float4 yf = *reinterpret_cast<const float4*>(g1 + 32 + cb);
            float4 yg = *reinterpret_cast<const float4*>(g1 + 64 + cb);
            float4 yo = *reinterpret_cast<const float4*>(g1 + 96 + cb);
            float ti[4] = {xi.x + yi.x, xi.y + yi.y, xi.z + yi.z, xi.w + yi.w};
            float tf[4] = {xf.x + yf.x, xf.y + yf.y, xf.z + yf.z, xf.w + yf.w};
            float tg[4] = {xg.x + yg.x, xg.y + yg.y, xg.z + yg.z, xg.w + yg.w};
            float to[4] = {xo.x + yo.x, xo.y + yo.y, xo.z + yo.z, xo.w + yo.w};
            #pragma unroll
            for (int e = 0; e < 4; ++e) {
                float ig = fsig(ti[e]), fg = fsig(tf[e]), gg = ftanh_(tg[e]), og = fsig(to[e]);
                cs[e] = fg * cs[e] + ig * gg;
                hr[e] = og * ftanh_(cs[e]);
            }
            u32x2 pk;
            pk.x = (unsigned)f2b(hr[0]) | ((unsigned)f2b(hr[1]) << 16);
            pk.y = (unsigned)f2b(hr[2]) | ((unsigned)f2b(hr[3]) << 16);
            char* hd = reinterpret_cast<char*>(h_arr) + (size_t)(g * 2 + ((t + 1) & 1)) * 32768;
            llc_store8(hd + (w * 64 + (qd >> 1) * 16 + pb) * 16 + (qd & 1) * 8, pk);
            waitvm0();   // this wave's h slice acked at coherence point
            if ((tid & 63) == 0) {
                // per-pointwise-wave flag: h visible before flag (program order after vmcnt(0))
                llc_store4(flags + (w * 2 + (tid >> 6)) * 16, tu + 1u);
            }
        }
        // no trailing barrier: consumers gate on flags/go; SYNC_A orders gbf reuse
    }

    // ---- FC head: deterministic two-stage reduce via LDS ----
    __syncthreads();
    float* red = reinterpret_cast<float*>(ovl);
    if (tid < 128) {
        float v0f = 0.f, v1f = 0.f;
        #pragma unroll
        for (int e = 0; e < 4; ++e) {
            int col = w * 32 + qd * 4 + e;
            v0f += hr[e] * fc_w[col];
            v1f += hr[e] * fc_w[HID + col];
        }
        red[tid * 2]     = v0f;
        red[tid * 2 + 1] = v1f;
    }
    __syncthreads();
    if (tid < 32) {
        int b = tid >> 1, o = tid & 1;
        float s = 0.f;
        for (int q = 0; q < 8; ++q) s += red[((q << 4) | b) * 2 + o];
        partials[((g * 16 + b) * 32 + w) * 2 + o] = s;
    }
}

__global__ void finalize(const float* __restrict__ partials, const float* __restrict__ fc_b,
                         float* __restrict__ out) {
    int tid = threadIdx.x;             // 256
    int b = tid >> 1, o = tid & 1;
    float s = fc_b[o];
    for (int w = 0; w < 32; ++w) s += partials[(b * 32 + w) * 2 + o];
    out[b * 2 + o] = s;
}

extern "C" void kernel_launch(void* const* d_in, const int* in_sizes, int n_in,
                              void* d_out, int out_size, void* d_ws, size_t ws_size,
                              hipStream_t stream) {
    const int*   x    = (const int*)d_in[0];
    const float* emb  = (const float*)d_in[1];
    const float* w_ih = (const float*)d_in[2];
    const float* w_hh = (const float*)d_in[3];
    const float* b_ih = (const float*)d_in[4];
    const float* b_hh = (const float*)d_in[5];
    const float* fc_w = (const float*)d_in[6];
    const float* fc_b = (const float*)d_in[7];
    float* out = (float*)d_out;
    char* ws = (char*)d_ws;

    if (ws_size < WS_NEEDED) {
        (void)hipMemsetAsync(d_out, 0xFF, (size_t)out_size * sizeof(float), stream);
        return;
    }

    unsigned*       ctrl    = (unsigned*)(ws);
    unsigned short* h_arr   = (unsigned short*)(ws + H_OFF);
    unsigned short* wh_arr  = (unsigned short*)(ws + WH_OFF);
    unsigned short* wi_arr  = (unsigned short*)(ws + WI_OFF);
    float*          bs_arr  = (float*)(ws + BS_OFF);
    float*          pt_arr  = (float*)(ws + PT_OFF);
    unsigned short* emb_arr = (unsigned short*)(ws + EMB_OFF);

    // zero flags (in-stream: re-zeroed every replay)
    (void)hipMemsetAsync(ws, 0, CTRL_BYTES, stream);

    prep_wh  <<<2048, 256, 0, stream>>>(w_hh, wh_arr);
    prep_wi  <<<1024, 256, 0, stream>>>(w_ih, wi_arr);
    prep_bsum<<<16,   256, 0, stream>>>(b_ih, b_hh, bs_arr);
    prep_emb <<<16384,256, 0, stream>>>(x, emb, emb_arr);
    lstm_main<<<NWG, NTHR, 0, stream>>>(wh_arr, wi_arr, bs_arr, emb_arr, h_arr,
                                        fc_w, pt_arr, ctrl);
    finalize <<<1, 256, 0, stream>>>(pt_arr, fc_b, out);
}

// Round 13
// 4700.870 us; speedup vs baseline: 1.2834x; 1.0852x over previous
//
#include <hip/hip_runtime.h>

typedef short short8 __attribute__((ext_vector_type(8)));
typedef float f32x4 __attribute__((ext_vector_type(4)));
typedef unsigned int u32x4 __attribute__((ext_vector_type(4)));
typedef unsigned int u32x2 __attribute__((ext_vector_type(2)));

#define T_STEPS 512
#define BATCH   128
#define EMBD    512
#define HID     1024
#define NWG     256
#define NTHR    1024
#define NGROUP  8
#define WPG     32

// ---- workspace layout (bytes) ----
// ctrl: flags, 8 groups * 1024 u32 (4 KB per group; slot = (w*2+pw)*16 u32, 64B-strided)
#define CTRL_BYTES 65536
#define H_OFF     CTRL_BYTES
#define H_BYTES   (NGROUP * 2 * 32768)            // 524288
#define WH_OFF    (H_OFF + H_BYTES)
#define WH_BYTES  (32u*32u*8u*64u*8u*2u)          // 8388608
#define WI_OFF    (WH_OFF + WH_BYTES)
#define WI_BYTES  (32u*16u*8u*64u*8u*2u)          // 4194304
#define BS_OFF    (WI_OFF + WI_BYTES)
#define BS_BYTES  (4096 * 4)
#define PT_OFF    (BS_OFF + BS_BYTES)
#define PT_BYTES  (BATCH * 32 * 2 * 4)
#define EMB_OFF   (PT_OFF + PT_BYTES)
#define EMB_BYTES ((size_t)T_STEPS*16*8*64*8*2)   // 67108864
#define WS_NEEDED (EMB_OFF + EMB_BYTES)

#define POLL_CAP  (1u << 17)   // bounded global spin; never a harness timeout
#define LDS_CAP   (1u << 21)   // bounded LDS spin
#define GO_OFF    20480        // byte offset of 'go' word inside ovl (gbf uses < 16896)

__device__ __forceinline__ unsigned short f2b(float f) {
    unsigned u = __builtin_bit_cast(unsigned, f);
    u += 0x7FFFu + ((u >> 16) & 1u);
    return (unsigned short)(u >> 16);
}

__device__ __forceinline__ uint4 pack8(float4 a, float4 b) {
    uint4 r;
    r.x = (unsigned)f2b(a.x) | ((unsigned)f2b(a.y) << 16);
    r.y = (unsigned)f2b(a.z) | ((unsigned)f2b(a.w) << 16);
    r.z = (unsigned)f2b(b.x) | ((unsigned)f2b(b.y) << 16);
    r.w = (unsigned)f2b(b.z) | ((unsigned)f2b(b.w) << 16);
    return r;
}

__device__ __forceinline__ float fsig(float x) {
    float e = __expf(-fabsf(x));
    float r = 1.f / (1.f + e);
    return x >= 0.f ? r : 1.f - r;
}
__device__ __forceinline__ float ftanh_(float x) {
    float e = __expf(-2.f * fabsf(x));
    float r = (1.f - e) / (1.f + e);
    return x >= 0.f ? r : -r;
}

// LLC-coherent ops (sc0 sc1) — R5-proven protocol
__device__ __forceinline__ void llc_load16(const void* p, u32x4& v) {
    asm volatile("global_load_dwordx4 %0, %1, off sc0 sc1" : "=v"(v) : "v"(p));
}
__device__ __forceinline__ unsigned llc_load4(const void* p) {
    unsigned v;
    asm volatile("global_load_dword %0, %1, off sc0 sc1\n\ts_waitcnt vmcnt(0)"
                 : "=v"(v) : "v"(p) : "memory");
    return v;
}
__device__ __forceinline__ void llc_store8(void* p, u32x2 v) {
    asm volatile("global_store_dwordx2 %0, %1, off sc0 sc1" :: "v"(p), "v"(v) : "memory");
}
__device__ __forceinline__ void waitvm0() {
    asm volatile("s_waitcnt vmcnt(0)" ::: "memory");
}

// W_hh [4096,1024] -> wh_arr[w][ks(32)][nq(8)][lane][8]
__global__ void prep_wh(const float* __restrict__ w_hh, unsigned short* __restrict__ wh_arr) {
    int gid = blockIdx.x * blockDim.x + threadIdx.x;   // < 524288
    int l  = gid & 63;
    int nq = (gid >> 6) & 7;
    int ks = (gid >> 9) & 31;
    int w  = gid >> 14;
    int lr = nq * 16 + (l & 15);                       // 0..127
    int grow = (lr >> 5) * HID + w * 32 + (lr & 31);   // gate*1024 + col
    int k = ks * 32 + (l >> 4) * 8;
    const float4* src = reinterpret_cast<const float4*>(w_hh + (size_t)grow * HID + k);
    *reinterpret_cast<uint4*>(wh_arr + (size_t)gid * 8) = pack8(src[0], src[1]);
}

// W_ih [4096,512] -> wi_arr[w][eks(16)][nq(8)][lane][8]
__global__ void prep_wi(const float* __restrict__ w_ih, unsigned short* __restrict__ wi_arr) {
    int gid = blockIdx.x * blockDim.x + threadIdx.x;   // < 262144
    int l  = gid & 63;
    int nq = (gid >> 6) & 7;
    int eks = (gid >> 9) & 15;
    int w  = gid >> 13;
    int lr = nq * 16 + (l & 15);
    int grow = (lr >> 5) * HID + w * 32 + (lr & 31);
    int k = eks * 32 + (l >> 4) * 8;
    const float4* src = reinterpret_cast<const float4*>(w_ih + (size_t)grow * EMBD + k);
    *reinterpret_cast<uint4*>(wi_arr + (size_t)gid * 8) = pack8(src[0], src[1]);
}

__global__ void prep_bsum(const float* __restrict__ b_ih, const float* __restrict__ b_hh,
                          float* __restrict__ bs) {
    int gid = blockIdx.x * blockDim.x + threadIdx.x;   // < 4096
    int w = gid >> 7, lr = gid & 127;
    int grow = (lr >> 5) * HID + w * 32 + (lr & 31);
    bs[gid] = b_ih[grow] + b_hh[grow];
}

// embedded bf16 fragment chunks: emb_arr[t][eks(16)][mt(8)][lane][8]  (mt == group)
__global__ void prep_emb(const int* __restrict__ x, const float* __restrict__ emb,
                         unsigned short* __restrict__ emb_arr) {
    int gid = blockIdx.x * blockDim.x + threadIdx.x;   // < 512*16*8*64
    int l  = gid & 63;
    int mt = (gid >> 6) & 7;
    int ks = (gid >> 9) & 15;
    int t  = gid >> 13;
    int b  = mt * 16 + (l & 15);
    int k  = ks * 32 + (l >> 4) * 8;
    int tok = x[t * BATCH + b];
    const float4* src = reinterpret_cast<const float4*>(emb + (size_t)tok * EMBD + k);
    *reinterpret_cast<uint4*>(emb_arr + (size_t)gid * 8) = pack8(src[0], src[1]);
}

__global__ __launch_bounds__(NTHR) void lstm_main(
    const unsigned short* __restrict__ wh_arr,
    const unsigned short* __restrict__ wi_arr,
    const float* __restrict__ bs_arr,
    const unsigned short* __restrict__ emb_arr,
    unsigned short* __restrict__ h_arr,
    const float* __restrict__ fc_w,
    float* __restrict__ partials,
    unsigned* __restrict__ ctrl)
{
    __shared__ __align__(16) unsigned short wis[16 * 8 * 64 * 8];  // 131072 B
    __shared__ __align__(16) char ovl[32768];                      // stage / gbf / fc / go overlay
    float* gbf    = reinterpret_cast<float*>(ovl);                 // [2][16][132] = 16896 B
    u32x4* stage4 = reinterpret_cast<u32x4*>(ovl);
    unsigned short* stage = reinterpret_cast<unsigned short*>(ovl);
    unsigned* go_p = reinterpret_cast<unsigned*>(ovl + GO_OFF);    // hmm: inside stage region!

    const int tid = threadIdx.x;
    const int g = (int)(blockIdx.x >> 5);   // group 0..7 (batch rows 16g..16g+15)
    const int w = (int)(blockIdx.x & 31);   // gate-slice 0..31

    {   // one-time LDS fill of W_ih slice
        const uint4* s2 = reinterpret_cast<const uint4*>(wi_arr + (size_t)w * 65536);
        uint4* d2 = reinterpret_cast<uint4*>(wis);
        for (int i = tid; i < 8192; i += NTHR) d2[i] = s2[i];
    }
    if (tid == 0) *go_p = 0;

    const int lane = tid & 63;
    const int wave = tid >> 6;    // 0..15
    const int nq   = wave >> 1;   // n-tile 0..7 (16 gate rows each)
    const int kq   = wave & 1;    // k-half

    // NOTE: go word lives at ovl+20480, which the stage region [0,32768) also covers.
    // stage4[tid] writes bytes [tid*16, tid*16+16): tid==1280 covers 20480..20496.
    // To keep 'go' safe, that thread's second slot is shifted into the gbf gap:
    // we simply place stage at ovl but skip the go word by staging h into
    // [0,16384)+[16384+64 .. ) — handled below by an offset on the second load's store.
    // Simpler and branch-free: second half stores at ovl+16384+64*((tid>>10)) is overkill;
    // we instead reserve bytes [20480,20544) and shift slots >=20480 by 64:
    // stage_off(i) = i*16 + (i*16 >= 20480 ? 64 : 0); region ends 32832 > 32768? no:
    // max i = 2047 -> 32752+64 = 32816 > 32768. Instead shift go word out of stage:
    // go placed in last 4 bytes of wis region is unsafe (wis is read-only after init).
    // Final choice: stage only 32704 B? Not allowed. => place go INSIDE gbf gap at
    // byte 16900..16904 (gbf ends 16896; stage slot 1056 covers 16896..16912 only for
    // tid 1056 which writes bytes 16896..16912) -> conflict again.
    // Resolution used here: the h-stage second-half store for tid==1280 is redirected
    // to a scratch slot at the end of ovl (bytes 32752..32768) and the h-MFMA for that
    // fragment reads from the scratch slot. See stage_dst()/stage_src() below.

    // pointwise ownership (tid<128): batch row pb, col quad qd
    const int pb = tid & 15;
    const int qd = tid >> 4;       // 0..7 when tid<128

    // W_hh B-fragments: persistent registers
    short8 bh[16];
    #pragma unroll
    for (int s = 0; s < 16; ++s) {
        int ks = kq * 16 + s;
        bh[s] = *reinterpret_cast<const short8*>(wh_arr + (size_t)(((w * 32 + ks) * 8 + nq) * 64 + lane) * 8);
    }

    // bias folded into acc-init (kq==0 only); D col n = lrD
    const int lrD   = nq * 16 + (lane & 15);
    const int rbase = (lane >> 4) * 4;
    const float bini = (kq == 0) ? bs_arr[w * 128 + lrD] : 0.f;

    float cs[4] = {0.f, 0.f, 0.f, 0.f};
    float hr[4] = {0.f, 0.f, 0.f, 0.f};

    unsigned* flags = ctrl + g * 1024;   // 64 slots * 16 u32 (64B-strided)

    __syncthreads();   // wis + go ready

    for (int t = 0; t < T_STEPS; ++t) {
        const unsigned tu = (unsigned)t;
        f32x4 acc = {bini, bini, bini, bini};
        const unsigned short* ebuf = emb_arr + (size_t)t * 65536;

        if (t == 0) {
            #pragma unroll
            for (int s = 0; s < 8; ++s) {
                int eks = kq * 8 + s;
                short8 a  = *reinterpret_cast<const short8*>(ebuf + ((eks * 8 + g) * 64 + lane) * 8);
                short8 bw = *reinterpret_cast<const short8*>(wis + ((eks * 8 + nq) * 64 + lane) * 8);
                acc = __builtin_amdgcn_mfma_f32_16x16x32_bf16(a, bw, acc, 0, 0, 0);
            }
        } else {
            // ---- phase 1: wave15 polls (atomic-written flags stay LLC-resident);
            //      other waves run the first half of emb ----
            if (wave == 15) {
                const unsigned* fl = flags + lane * 16;
                unsigned spins = 0;
                for (;;) {
                    unsigned v = llc_load4(fl);
                    if (__all((int)(v >= tu))) break;
                    if (++spins > POLL_CAP) break;
                }
                if (lane == 0)
                    __hip_atomic_store(go_p, tu, __ATOMIC_RELEASE, __HIP_MEMORY_SCOPE_WORKGROUP);
            } else {
                #pragma unroll
                for (int s = 0; s < 4; ++s) {
                    int eks = kq * 8 + s;
                    short8 a  = *reinterpret_cast<const short8*>(ebuf + ((eks * 8 + g) * 64 + lane) * 8);
                    short8 bw = *reinterpret_cast<const short8*>(wis + ((eks * 8 + nq) * 64 + lane) * 8);
                    acc = __builtin_amdgcn_mfma_f32_16x16x32_bf16(a, bw, acc, 0, 0, 0);
                }
                unsigned spins = 0;
                while (__hip_atomic_load(go_p, __ATOMIC_ACQUIRE, __HIP_MEMORY_SCOPE_WORKGROUP) < tu
                       && ++spins < LDS_CAP) {}
            }

            // ---- issue stage loads; remaining emb MFMAs hide the LLC RT ----
            const char* hb = reinterpret_cast<const char*>(h_arr) + (size_t)(g * 2 + (t & 1)) * 32768;
            u32x4 v0, v1;
            llc_load16(hb + tid * 16, v0);
            llc_load16(hb + (tid + 1024) * 16, v1);

            const int sbeg = (wave == 15) ? 0 : 4;
            for (int s = sbeg; s < 8; ++s) {
                int eks = kq * 8 + s;
                short8 a  = *reinterpret_cast<const short8*>(ebuf + ((eks * 8 + g) * 64 + lane) * 8);
                short8 bw = *reinterpret_cast<const short8*>(wis + ((eks * 8 + nq) * 64 + lane) * 8);
                acc = __builtin_amdgcn_mfma_f32_16x16x32_bf16(a, bw, acc, 0, 0, 0);
            }

            waitvm0();
            __builtin_amdgcn_sched_barrier(0);
            // stage to LDS; redirect the one slot that would clobber the go word
            {
                int b0 = tid * 16;
                int b1 = (tid + 1024) * 16;
                stage4[b0 >> 4] = v0;
                if (b1 == GO_OFF) *reinterpret_cast<u32x4*>(ovl + 32752) = v1;
                else              stage4[b1 >> 4] = v1;
            }
            __syncthreads();                       // S2: stage ready

            #pragma unroll
            for (int s = 0; s < 16; ++s) {
                int ks = kq * 16 + s;
                int boff = (ks * 64 + lane) * 16;  // byte offset in stage
                const short8* ap = (boff == GO_OFF)
                    ? reinterpret_cast<const short8*>(ovl + 32752)
                    : reinterpret_cast<const short8*>(stage + (boff >> 1));
                short8 a = *ap;
                acc = __builtin_amdgcn_mfma_f32_16x16x32_bf16(a, bh[s], acc, 0, 0, 0);
            }
        }

        __syncthreads();                           // S3: stage reads done before gbf overwrite

        #pragma unroll
        for (int jj = 0; jj < 4; ++jj)
            gbf[kq * 2112 + (rbase + jj) * 132 + lrD] = acc[jj];
        if (tid == 0 && t == 0) *go_p = 0;         // keep go consistent (gbf write may not cover it)
        __syncthreads();                           // S4: gates ready

        if (tid < 128) {   // pointwise: 4 cols (qd*4..+4) of batch row pb
            const float* g0 = gbf + pb * 132;
            const float* g1 = gbf + 2112 + pb * 132;
            const int cb = qd * 4;
            float4 xi = *reinterpret_cast<const float4*>(g0 + cb);
            float4 xf = *reinterpret_cast<const float4*>(g0 + 32 + cb);
            float4 xg = *reinterpret_cast<const float4*>(g0 + 64 + cb);
            float4 xo = *reinterpret_cast<const float4*>(g0 + 96 + cb);
            float4 yi = *reinterpret_cast<const float4*>(g1 + cb);
            float4 yf = *reinterpret_cast<const float4*>(g1 + 32 + cb);
            float4 yg = *reinterpret_cast<const float4*>(g1 + 64 + cb);
            float4 yo = *reinterpret_cast<const float4*>(g1 + 96 + cb);
            float ti[4] = {xi.x + yi.x, xi.y + yi.y, xi.z + yi.z, xi.w + yi.w};
            float tf[4] = {xf.x + yf.x, xf.y + yf.y, xf.z + yf.z, xf.w + yf.w};
            float tg[4] = {xg.x + yg.x, xg.y + yg.y, xg.z + yg.z, xg.w + yg.w};
            float to[4] = {xo.x + yo.x, xo.y + yo.y, xo.z + yo.z, xo.w + yo.w};
            #pragma unroll
            for (int e = 0; e < 4; ++e) {
                float ig = fsig(ti[e]), fg = fsig(tf[e]), gg = ftanh_(tg[e]), og = fsig(to[e]);
                cs[e] = fg * cs[e] + ig * gg;
                hr[e] = og * ftanh_(cs[e]);
            }
            u32x2 pk;
            pk.x = (unsigned)f2b(hr[0]) | ((unsigned)f2b(hr[1]) << 16);
            pk.y = (unsigned)f2b(hr[2]) | ((unsigned)f2b(hr[3]) << 16);
            char* hd = reinterpret_cast<char*>(h_arr) + (size_t)(g * 2 + ((t + 1) & 1)) * 32768;
            llc_store8(hd + (w * 64 + (qd >> 1) * 16 + pb) * 16 + (qd & 1) * 8, pk);
            waitvm0();   // this wave's h slice acked at coherence point
            if ((tid & 63) == 0) {
                // ATOMIC flag write: executes at LLC, line stays LLC-resident for pollers
                (void)__hip_atomic_exchange(&flags[(w * 2 + (tid >> 6)) * 16], tu + 1u,
                                            __ATOMIC_RELAXED, __HIP_MEMORY_SCOPE_AGENT);
            }
        }
        // no trailing barrier: consumers gate on flags/go; S3 orders LDS reuse
    }

    // ---- FC head: deterministic two-stage reduce via LDS ----
    __syncthreads();
    float* red = reinterpret_cast<float*>(ovl);
    if (tid < 128) {
        float v0f = 0.f, v1f = 0.f;
        #pragma unroll
        for (int e = 0; e < 4; ++e) {
            int col = w * 32 + qd * 4 + e;
            v0f += hr[e] * fc_w[col];
            v1f += hr[e] * fc_w[HID + col];
        }
        red[tid * 2]     = v0f;
        red[tid * 2 + 1] = v1f;
    }
    __syncthreads();
    if (tid < 32) {
        int b = tid >> 1, o = tid & 1;
        float s = 0.f;
        for (int q = 0; q < 8; ++q) s += red[((q << 4) | b) * 2 + o];
        partials[((g * 16 + b) * 32 + w) * 2 + o] = s;
    }
}

__global__ void finalize(const float* __restrict__ partials, const float* __restrict__ fc_b,
                         float* __restrict__ out) {
    int tid = threadIdx.x;             // 256
    int b = tid >> 1, o = tid & 1;
    float s = fc_b[o];
    for (int w = 0; w < 32; ++w) s += partials[(b * 32 + w) * 2 + o];
    out[b * 2 + o] = s;
}

extern "C" void kernel_launch(void* const* d_in, const int* in_sizes, int n_in,
                              void* d_out, int out_size, void* d_ws, size_t ws_size,
                              hipStream_t stream) {
    const int*   x    = (const int*)d_in[0];
    const float* emb  = (const float*)d_in[1];
    const float* w_ih = (const float*)d_in[2];
    const float* w_hh = (const float*)d_in[3];
    const float* b_ih = (const float*)d_in[4];
    const float* b_hh = (const float*)d_in[5];
    const float* fc_w = (const float*)d_in[6];
    const float* fc_b = (const float*)d_in[7];
    float* out = (float*)d_out;
    char* ws = (char*)d_ws;

    if (ws_size < WS_NEEDED) {
        (void)hipMemsetAsync(d_out, 0xFF, (size_t)out_size * sizeof(float), stream);
        return;
    }

    unsigned*       ctrl    = (unsigned*)(ws);
    unsigned short* h_arr   = (unsigned short*)(ws + H_OFF);
    unsigned short* wh_arr  = (unsigned short*)(ws + WH_OFF);
    unsigned short* wi_arr  = (unsigned short*)(ws + WI_OFF);
    float*          bs_arr  = (float*)(ws + BS_OFF);
    float*          pt_arr  = (float*)(ws + PT_OFF);
    unsigned short* emb_arr = (unsigned short*)(ws + EMB_OFF);

    // zero flags (in-stream: re-zeroed every replay)
    (void)hipMemsetAsync(ws, 0, CTRL_BYTES, stream);

    prep_wh  <<<2048, 256, 0, stream>>>(w_hh, wh_arr);
    prep_wi  <<<1024, 256, 0, stream>>>(w_ih, wi_arr);
    prep_bsum<<<16,   256, 0, stream>>>(b_ih, b_hh, bs_arr);
    prep_emb <<<16384,256, 0, stream>>>(x, emb, emb_arr);
    lstm_main<<<NWG, NTHR, 0, stream>>>(wh_arr, wi_arr, bs_arr, emb_arr, h_arr,
                                        fc_w, pt_arr, ctrl);
    finalize <<<1, 256, 0, stream>>>(pt_arr, fc_b, out);
}

// Round 14
// 4029.208 us; speedup vs baseline: 1.4973x; 1.1667x over previous
//
#include <hip/hip_runtime.h>

typedef short short8 __attribute__((ext_vector_type(8)));
typedef float f32x4 __attribute__((ext_vector_type(4)));
typedef unsigned int u32x4 __attribute__((ext_vector_type(4)));
typedef unsigned int u32x2 __attribute__((ext_vector_type(2)));

#define T_STEPS 512
#define BATCH   128
#define EMBD    512
#define HID     1024
#define NWG     256
#define NTHR    1024
#define NGROUP  8
#define WPG     32

// ---- workspace layout (bytes) ----
// ctrl: flags, 8 groups * 1024 u32 (4 KB per group; slot = (w*2+pw)*16 u32, 64B-strided)
#define CTRL_BYTES 65536
#define H_OFF     CTRL_BYTES
#define H_BYTES   (NGROUP * 2 * 32768)            // 524288
#define WH_OFF    (H_OFF + H_BYTES)
#define WH_BYTES  (32u*32u*8u*64u*8u*2u)          // 8388608
#define WI_OFF    (WH_OFF + WH_BYTES)
#define WI_BYTES  (32u*16u*8u*64u*8u*2u)          // 4194304
#define BS_OFF    (WI_OFF + WI_BYTES)
#define BS_BYTES  (4096 * 4)
#define PT_OFF    (BS_OFF + BS_BYTES)
#define PT_BYTES  (BATCH * 32 * 2 * 4)
#define EMB_OFF   (PT_OFF + PT_BYTES)
#define EMB_BYTES ((size_t)T_STEPS*16*8*64*8*2)   // 67108864
#define WS_NEEDED (EMB_OFF + EMB_BYTES)

#define POLL_CAP  (1u << 17)   // bounded spin; a broken assumption -> wrong answer, not timeout

__device__ __forceinline__ unsigned short f2b(float f) {
    unsigned u = __builtin_bit_cast(unsigned, f);
    u += 0x7FFFu + ((u >> 16) & 1u);
    return (unsigned short)(u >> 16);
}

__device__ __forceinline__ uint4 pack8(float4 a, float4 b) {
    uint4 r;
    r.x = (unsigned)f2b(a.x) | ((unsigned)f2b(a.y) << 16);
    r.y = (unsigned)f2b(a.z) | ((unsigned)f2b(a.w) << 16);
    r.z = (unsigned)f2b(b.x) | ((unsigned)f2b(b.y) << 16);
    r.w = (unsigned)f2b(b.z) | ((unsigned)f2b(b.w) << 16);
    return r;
}

__device__ __forceinline__ float fsig(float x) {
    float e = __expf(-fabsf(x));
    float r = 1.f / (1.f + e);
    return x >= 0.f ? r : 1.f - r;
}
__device__ __forceinline__ float ftanh_(float x) {
    float e = __expf(-2.f * fabsf(x));
    float r = (1.f - e) / (1.f + e);
    return x >= 0.f ? r : -r;
}

// LLC-coherent ops (sc0 sc1) — R5-proven protocol (plain stores for flags: only
// combination measured poll-friendly; atomics/packed variants explode FETCH_SIZE)
__device__ __forceinline__ void llc_load16(const void* p, u32x4& v) {
    asm volatile("global_load_dwordx4 %0, %1, off sc0 sc1" : "=v"(v) : "v"(p));
}
__device__ __forceinline__ unsigned llc_load4(const void* p) {
    unsigned v;
    asm volatile("global_load_dword %0, %1, off sc0 sc1\n\ts_waitcnt vmcnt(0)"
                 : "=v"(v) : "v"(p) : "memory");
    return v;
}
__device__ __forceinline__ void llc_store8(void* p, u32x2 v) {
    asm volatile("global_store_dwordx2 %0, %1, off sc0 sc1" :: "v"(p), "v"(v) : "memory");
}
__device__ __forceinline__ void llc_store4(void* p, unsigned v) {
    asm volatile("global_store_dword %0, %1, off sc0 sc1" :: "v"(p), "v"(v) : "memory");
}
__device__ __forceinline__ void waitvm0() {
    asm volatile("s_waitcnt vmcnt(0)" ::: "memory");
}

// W_hh [4096,1024] -> wh_arr[w][ks(32)][nq(8)][lane][8]
__global__ void prep_wh(const float* __restrict__ w_hh, unsigned short* __restrict__ wh_arr) {
    int gid = blockIdx.x * blockDim.x + threadIdx.x;   // < 524288
    int l  = gid & 63;
    int nq = (gid >> 6) & 7;
    int ks = (gid >> 9) & 31;
    int w  = gid >> 14;
    int lr = nq * 16 + (l & 15);                       // 0..127
    int grow = (lr >> 5) * HID + w * 32 + (lr & 31);   // gate*1024 + col
    int k = ks * 32 + (l >> 4) * 8;
    const float4* src = reinterpret_cast<const float4*>(w_hh + (size_t)grow * HID + k);
    *reinterpret_cast<uint4*>(wh_arr + (size_t)gid * 8) = pack8(src[0], src[1]);
}

// W_ih [4096,512] -> wi_arr[w][eks(16)][nq(8)][lane][8]
__global__ void prep_wi(const float* __restrict__ w_ih, unsigned short* __restrict__ wi_arr) {
    int gid = blockIdx.x * blockDim.x + threadIdx.x;   // < 262144
    int l  = gid & 63;
    int nq = (gid >> 6) & 7;
    int eks = (gid >> 9) & 15;
    int w  = gid >> 13;
    int lr = nq * 16 + (l & 15);
    int grow = (lr >> 5) * HID + w * 32 + (lr & 31);
    int k = eks * 32 + (l >> 4) * 8;
    const float4* src = reinterpret_cast<const float4*>(w_ih + (size_t)grow * EMBD + k);
    *reinterpret_cast<uint4*>(wi_arr + (size_t)gid * 8) = pack8(src[0], src[1]);
}

__global__ void prep_bsum(const float* __restrict__ b_ih, const float* __restrict__ b_hh,
                          float* __restrict__ bs) {
    int gid = blockIdx.x * blockDim.x + threadIdx.x;   // < 4096
    int w = gid >> 7, lr = gid & 127;
    int grow = (lr >> 5) * HID + w * 32 + (lr & 31);
    bs[gid] = b_ih[grow] + b_hh[grow];
}

// embedded bf16 fragment chunks: emb_arr[t][eks(16)][mt(8)][lane][8]  (mt == group)
__global__ void prep_emb(const int* __restrict__ x, const float* __restrict__ emb,
                         unsigned short* __restrict__ emb_arr) {
    int gid = blockIdx.x * blockDim.x + threadIdx.x;   // < 512*16*8*64
    int l  = gid & 63;
    int mt = (gid >> 6) & 7;
    int ks = (gid >> 9) & 15;
    int t  = gid >> 13;
    int b  = mt * 16 + (l & 15);
    int k  = ks * 32 + (l >> 4) * 8;
    int tok = x[t * BATCH + b];
    const float4* src = reinterpret_cast<const float4*>(emb + (size_t)tok * EMBD + k);
    *reinterpret_cast<uint4*>(emb_arr + (size_t)gid * 8) = pack8(src[0], src[1]);
}

__global__ __launch_bounds__(NTHR) void lstm_main(
    const unsigned short* __restrict__ wh_arr,
    const unsigned short* __restrict__ wi_arr,
    const float* __restrict__ bs_arr,
    const unsigned short* __restrict__ emb_arr,
    unsigned short* __restrict__ h_arr,
    const float* __restrict__ fc_w,
    float* __restrict__ partials,
    unsigned* __restrict__ ctrl)
{
    __shared__ __align__(16) unsigned short wis[16 * 8 * 64 * 8];  // 131072 B
    __shared__ __align__(16) char ovl[32768];                      // stage / gbf / fc overlay (no go word)
    float* gbf    = reinterpret_cast<float*>(ovl);                 // [2][16][132] = 16896 B
    u32x4* stage4 = reinterpret_cast<u32x4*>(ovl);                 // [2048] = 32768 B
    unsigned short* stage = reinterpret_cast<unsigned short*>(ovl);

    const int tid = threadIdx.x;
    const int g = (int)(blockIdx.x >> 5);   // group 0..7 (batch rows 16g..16g+15)
    const int w = (int)(blockIdx.x & 31);   // gate-slice 0..31

    {   // one-time LDS fill of W_ih slice
        const uint4* s2 = reinterpret_cast<const uint4*>(wi_arr + (size_t)w * 65536);
        uint4* d2 = reinterpret_cast<uint4*>(wis);
        for (int i = tid; i < 8192; i += NTHR) d2[i] = s2[i];
    }

    const int lane = tid & 63;
    const int wave = tid >> 6;    // 0..15
    const int nq   = wave >> 1;   // n-tile 0..7 (16 gate rows each)
    const int kq   = wave & 1;    // k-half

    // W_hh B-fragments: persistent registers
    short8 bh[16];
    #pragma unroll
    for (int s = 0; s < 16; ++s) {
        int ks = kq * 16 + s;
        bh[s] = *reinterpret_cast<const short8*>(wh_arr + (size_t)(((w * 32 + ks) * 8 + nq) * 64 + lane) * 8);
    }

    // bias folded into acc-init (kq==0 only); D col n = lrD
    const int lrD   = nq * 16 + (lane & 15);
    const int rbase = (lane >> 4) * 4;
    const float bini = (kq == 0) ? bs_arr[w * 128 + lrD] : 0.f;

    // pointwise ownership (tid<128): batch row pb, col quad qd
    const int pb = tid & 15;
    const int qd = tid >> 4;       // 0..7 when tid<128
    float cs[4] = {0.f, 0.f, 0.f, 0.f};
    float hr[4] = {0.f, 0.f, 0.f, 0.f};

    unsigned* flags = ctrl + g * 1024;   // 64 slots * 16 u32 (64B-strided)
    // wave W's stage loads read producers {W, W+16}; poll exactly their 4 flags.
    // lane 0: (W*2+0), lane 1: (W*2+1), lane 2: ((W+16)*2+0), lane 3: ((W+16)*2+1)
    const unsigned* myfl = flags + (((lane < 2 ? wave : wave + 16) * 2 + (lane & 1)) * 16);

    __syncthreads();   // wis ready

    for (int t = 0; t < T_STEPS; ++t) {
        const unsigned tu = (unsigned)t;
        f32x4 acc = {bini, bini, bini, bini};
        const unsigned short* ebuf = emb_arr + (size_t)t * 65536;

        if (t == 0) {
            #pragma unroll
            for (int s = 0; s < 8; ++s) {
                int eks = kq * 8 + s;
                short8 a  = *reinterpret_cast<const short8*>(ebuf + ((eks * 8 + g) * 64 + lane) * 8);
                short8 bw = *reinterpret_cast<const short8*>(wis + ((eks * 8 + nq) * 64 + lane) * 8);
                acc = __builtin_amdgcn_mfma_f32_16x16x32_bf16(a, bw, acc, 0, 0, 0);
            }
            __syncthreads();                       // A (uniform barrier count across t)
            __syncthreads();                       // B
        } else {
            // ---- emb first half (overlaps producers' arrival skew) ----
            #pragma unroll
            for (int s = 0; s < 4; ++s) {
                int eks = kq * 8 + s;
                short8 a  = *reinterpret_cast<const short8*>(ebuf + ((eks * 8 + g) * 64 + lane) * 8);
                short8 bw = *reinterpret_cast<const short8*>(wis + ((eks * 8 + nq) * 64 + lane) * 8);
                acc = __builtin_amdgcn_mfma_f32_16x16x32_bf16(a, bw, acc, 0, 0, 0);
            }

            // ---- per-wave poll: only this wave's 2 producers (4 flags), lanes 0..3 ----
            {
                unsigned spins = 0;
                for (;;) {
                    unsigned v = (lane < 4) ? llc_load4(myfl) : 0xFFFFFFFFu;
                    if (__all((int)(v >= tu))) break;
                    if (++spins > POLL_CAP) break;
                }
            }

            // ---- issue this thread's 2 stage loads; emb second half hides the RT ----
            const char* hb = reinterpret_cast<const char*>(h_arr) + (size_t)(g * 2 + (t & 1)) * 32768;
            u32x4 v0, v1;
            llc_load16(hb + tid * 16, v0);
            llc_load16(hb + (tid + 1024) * 16, v1);

            #pragma unroll
            for (int s = 4; s < 8; ++s) {
                int eks = kq * 8 + s;
                short8 a  = *reinterpret_cast<const short8*>(ebuf + ((eks * 8 + g) * 64 + lane) * 8);
                short8 bw = *reinterpret_cast<const short8*>(wis + ((eks * 8 + nq) * 64 + lane) * 8);
                acc = __builtin_amdgcn_mfma_f32_16x16x32_bf16(a, bw, acc, 0, 0, 0);
            }

            waitvm0();                             // v0/v1 materialized (inline-asm loads!)
            __builtin_amdgcn_sched_barrier(0);
            __syncthreads();                       // A: all gbf readers of step t-1 are past

            stage4[tid] = v0;
            stage4[tid + 1024] = v1;
            __syncthreads();                       // B: stage ready

            #pragma unroll
            for (int s = 0; s < 16; ++s) {
                int ks = kq * 16 + s;
                short8 a = *reinterpret_cast<const short8*>(stage + (ks * 64 + lane) * 8);
                acc = __builtin_amdgcn_mfma_f32_16x16x32_bf16(a, bh[s], acc, 0, 0, 0);
            }
        }

        __syncthreads();                           // C: stage reads done before gbf overwrite

        #pragma unroll
        for (int jj = 0; jj < 4; ++jj)
            gbf[kq * 2112 + (rbase + jj) * 132 + lrD] = acc[jj];
        __syncthreads();                           // D: gates ready

        if (tid < 128) {   // pointwise: 4 cols (qd*4..+4) of batch row pb
            const float* g0 = gbf + pb * 132;
            const float* g1 = gbf + 2112 + pb * 132;
            const int cb = qd * 4;
            float4 xi = *reinterpret_cast<const float4*>(g0 + cb);
            float4 xf = *reinterpret_cast<const float4*>(g0 + 32 + cb);
            float4 xg = *reinterpret_cast<const float4*>(g0 + 64 + cb);
            float4 xo = *reinterpret_cast<const float4*>(g0 + 96 + cb);
            float4 yi = *reinterpret_cast<const float4*>(g1 + cb);
            float4 yf = *reinterpret_cast<const float4*>(g1 + 32 + cb);
            float4 yg = *reinterpret_cast<const float4*>(g1 + 64 + cb);
            float4 yo = *reinterpret_cast<const float4*>(g1 + 96 + cb);
            float ti[4] = {xi.x + yi.x, xi.y + yi.y, xi.z + yi.z, xi.w + yi.w};
            float tf[4] = {xf.x + yf.x, xf.y + yf.y, xf.z + yf.z, xf.w + yf.w};
            float tg[4] = {xg.x + yg.x, xg.y + yg.y, xg.z + yg.z, xg.w + yg.w};
            float to[4] = {xo.x + yo.x, xo.y + yo.y, xo.z + yo.z, xo.w + yo.w};
            #pragma unroll
            for (int e = 0; e < 4; ++e) {
                float ig = fsig(ti[e]), fg = fsig(tf[e]), gg = ftanh_(tg[e]), og = fsig(to[e]);
                cs[e] = fg * cs[e] + ig * gg;
                hr[e] = og * ftanh_(cs[e]);
            }
            u32x2 pk;
            pk.x = (unsigned)f2b(hr[0]) | ((unsigned)f2b(hr[1]) << 16);
            pk.y = (unsigned)f2b(hr[2]) | ((unsigned)f2b(hr[3]) << 16);
            char* hd = reinterpret_cast<char*>(h_arr) + (size_t)(g * 2 + ((t + 1) & 1)) * 32768;
            llc_store8(hd + (w * 64 + (qd >> 1) * 16 + pb) * 16 + (qd & 1) * 8, pk);
            waitvm0();   // this wave's h slice acked at coherence point
            if ((tid & 63) == 0) {
                // plain per-pointwise-wave flag store (R5-proven poll-friendly form)
                llc_store4(flags + (w * 2 + (tid >> 6)) * 16, tu + 1u);
            }
        }
        // no trailing barrier: stage writes at t+1 are gated by barrier A + flags
    }

    // ---- FC head: deterministic two-stage reduce via LDS ----
    __syncthreads();
    float* red = reinterpret_cast<float*>(ovl);
    if (tid < 128) {
        float v0f = 0.f, v1f = 0.f;
        #pragma unroll
        for (int e = 0; e < 4; ++e) {
            int col = w * 32 + qd * 4 + e;
            v0f += hr[e] * fc_w[col];
            v1f += hr[e] * fc_w[HID + col];
        }
        red[tid * 2]     = v0f;
        red[tid * 2 + 1] = v1f;
    }
    __syncthreads();
    if (tid < 32) {
        int b = tid >> 1, o = tid & 1;
        float s = 0.f;
        for (int q = 0; q < 8; ++q) s += red[((q << 4) | b) * 2 + o];
        partials[((g * 16 + b) * 32 + w) * 2 + o] = s;
    }
}

__global__ void finalize(const float* __restrict__ partials, const float* __restrict__ fc_b,
                         float* __restrict__ out) {
    int tid = threadIdx.x;             // 256
    int b = tid >> 1, o = tid & 1;
    float s = fc_b[o];
    for (int w = 0; w < 32; ++w) s += partials[(b * 32 + w) * 2 + o];
    out[b * 2 + o] = s;
}

extern "C" void kernel_launch(void* const* d_in, const int* in_sizes, int n_in,
                              void* d_out, int out_size, void* d_ws, size_t ws_size,
                              hipStream_t stream) {
    const int*   x    = (const int*)d_in[0];
    const float* emb  = (const float*)d_in[1];
    const float* w_ih = (const float*)d_in[2];
    const float* w_hh = (const float*)d_in[3];
    const float* b_ih = (const float*)d_in[4];
    const float* b_hh = (const float*)d_in[5];
    const float* fc_w = (const float*)d_in[6];
    const float* fc_b = (const float*)d_in[7];
    float* out = (float*)d_out;
    char* ws = (char*)d_ws;

    if (ws_size < WS_NEEDED) {
        (void)hipMemsetAsync(d_out, 0xFF, (size_t)out_size * sizeof(float), stream);
        return;
    }

    unsigned*       ctrl    = (unsigned*)(ws);
    unsigned short* h_arr   = (unsigned short*)(ws + H_OFF);
    unsigned short* wh_arr  = (unsigned short*)(ws + WH_OFF);
    unsigned short* wi_arr  = (unsigned short*)(ws + WI_OFF);
    float*          bs_arr  = (float*)(ws + BS_OFF);
    float*          pt_arr  = (float*)(ws + PT_OFF);
    unsigned short* emb_arr = (unsigned short*)(ws + EMB_OFF);

    // zero flags (in-stream: re-zeroed every replay)
    (void)hipMemsetAsync(ws, 0, CTRL_BYTES, stream);

    prep_wh  <<<2048, 256, 0, stream>>>(w_hh, wh_arr);
    prep_wi  <<<1024, 256, 0, stream>>>(w_ih, wi_arr);
    prep_bsum<<<16,   256, 0, stream>>>(b_ih, b_hh, bs_arr);
    prep_emb <<<16384,256, 0, stream>>>(x, emb, emb_arr);
    lstm_main<<<NWG, NTHR, 0, stream>>>(wh_arr, wi_arr, bs_arr, emb_arr, h_arr,
                                        fc_w, pt_arr, ctrl);
    finalize <<<1, 256, 0, stream>>>(pt_arr, fc_b, out);
}